// Round 8
// baseline (63.521 us; speedup 1.0000x reference)
//
#include <hip/hip_runtime.h>
#include <math.h>

// Problem constants (match reference)
#define B_ 32
#define T_ 8192
#define C_ 64
#define S_ 256           // t-chunks per batch row (chunk = 32 t = one wave's job)
#define L_ 32
#define EPS_ 1e-8f
#define SIGMA_MIN_ 1e-4f

// Workspace layout (float offsets); chunks = B_*S_ = 8192
#define SUM_OFF  0                       // 8192*64 = 524288
#define SQ_OFF   524288
#define MS_OFF   1048576
#define GAP_OFF  1572864                 // 8192 int4 = 32768 ints
#define BITS_OFF 1605632                 // 65536 rows * 4 u64 = 524288 floats
#define MU_OFF   2129920                 // B_*C_ = 2048
#define INV_OFF  2131968                 // 2048
// total = 2134016 floats ~= 8.1 MiB

__device__ inline float4 f4add(float4 a, float4 b) {
    return make_float4(a.x + b.x, a.y + b.y, a.z + b.z, a.w + b.w);
}
__device__ inline float4 f4shfl_xor(float4 v, int m) {
    float4 r;
    r.x = __shfl_xor(v.x, m);
    r.y = __shfl_xor(v.y, m);
    r.z = __shfl_xor(v.z, m);
    r.w = __shfl_xor(v.w, m);
    return r;
}
// ordered merge of run-tuples: acc(l) then r
__device__ inline void merge_lr(int l_pre, int l_suf, int l_best, int l_len,
                                int r_pre, int r_suf, int r_best, int r_len,
                                int& pre, int& suf, int& best, int& len) {
    best = max(max(l_best, r_best), l_suf + r_pre);
    pre  = (l_pre == l_len) ? l_len + r_pre : l_pre;
    suf  = (r_suf == r_len) ? r_len + l_suf : r_suf;
    len  = l_len + r_len;
}

// -------- Kernel 1x: x-only stats (mask*x == x, mask*x^2 == x^2) -------------
// Wave gw owns chunk gw (32 t): 8 iters of 64 consecutive float4s (4 KB/iter).
__global__ __launch_bounds__(256) void k1x_stats(const float* __restrict__ x,
                                                 float* __restrict__ ws) {
    const int wv   = threadIdx.x >> 6;
    const int lane = threadIdx.x & 63;
    const int gw   = blockIdx.x * 4 + wv;      // chunk id 0..8191
    const int base = gw * 512 + lane;          // float4 index

    const float4* x4 = (const float4*)x;
    float4 s1 = make_float4(0.f, 0.f, 0.f, 0.f);
    float4 s2 = make_float4(0.f, 0.f, 0.f, 0.f);
#pragma unroll
    for (int it = 0; it < 8; ++it) {
        const float4 xv = x4[base + it * 64];
        s1.x += xv.x; s1.y += xv.y; s1.z += xv.z; s1.w += xv.w;
        s2.x += xv.x * xv.x; s2.y += xv.y * xv.y;
        s2.z += xv.z * xv.z; s2.w += xv.w * xv.w;
    }
    s1 = f4add(s1, f4shfl_xor(s1, 16)); s1 = f4add(s1, f4shfl_xor(s1, 32));
    s2 = f4add(s2, f4shfl_xor(s2, 16)); s2 = f4add(s2, f4shfl_xor(s2, 32));
    if (lane < 16) {
        ((float4*)(ws + SUM_OFF))[gw * 16 + lane] = s1;
        ((float4*)(ws + SQ_OFF ))[gw * 16 + lane] = s2;
    }
}

// -------- Kernel 1m: mask-only -> counts, bit-pack, gap tuple ----------------
__global__ __launch_bounds__(256) void k1m_stats(const float* __restrict__ mask,
                                                 float* __restrict__ ws) {
    const int wv   = threadIdx.x >> 6;
    const int lane = threadIdx.x & 63;
    const int gw   = blockIdx.x * 4 + wv;      // chunk id 0..8191
    const int base = gw * 512 + lane;          // float4 index

    const float4* m4 = (const float4*)mask;
    unsigned long long* bits = (unsigned long long*)(ws + BITS_OFF);

    float4 sm = make_float4(0.f, 0.f, 0.f, 0.f);
    unsigned int missw = 0;
#pragma unroll
    for (int it = 0; it < 8; ++it) {
        const float4 mv = m4[base + it * 64];
        sm.x += mv.x; sm.y += mv.y; sm.z += mv.z; sm.w += mv.w;

        // observed-bit words (1 = observed); bit index == lane
        unsigned long long obx = __ballot(mv.x >= 0.5f);
        unsigned long long oby = __ballot(mv.y >= 0.5f);
        unsigned long long obz = __ballot(mv.z >= 0.5f);
        unsigned long long obw = __ballot(mv.w >= 0.5f);
        if (lane < 4) {
            unsigned long long v = (lane == 0) ? obx : (lane == 1) ? oby
                                 : (lane == 2) ? obz : obw;
            bits[(size_t)(gw * 8 + it) * 4 + lane] = v;   // one 32B row / iter
        }
        // channel-0 missing bits live at lanes 0,16,32,48 of ~obx
        const unsigned long long nm = ~obx;
        const unsigned int nib =
              (unsigned int)(nm & 1ull)
            | ((unsigned int)((nm >> 16) & 1ull) << 1)
            | ((unsigned int)((nm >> 32) & 1ull) << 2)
            | ((unsigned int)((nm >> 48) & 1ull) << 3);
        missw |= nib << (it * 4);
    }

    sm = f4add(sm, f4shfl_xor(sm, 16)); sm = f4add(sm, f4shfl_xor(sm, 32));
    if (lane < 16)
        ((float4*)(ws + MS_OFF))[gw * 16 + lane] = sm;

    if (lane == 0) {
        const unsigned int w = missw;      // bit i = chunk-local t missing
        int pre, suf, best;
        if (w == 0xFFFFFFFFu) {
            pre = 32; suf = 32; best = 32;
        } else {
            pre = __builtin_ctz(~w);
            suf = __builtin_clz(~w);
            unsigned int tmp = w; best = 0;
            while (tmp) { tmp &= (tmp << 1); ++best; }
        }
        ((int4*)((int*)(ws + GAP_OFF)))[gw] = make_int4(pre, suf, best, L_);
    }
}

// ---------------- Kernel 2: combine partials -> per-(b,c) mu, 1/sigma --------
__global__ __launch_bounds__(256) void k2_params(const int*   __restrict__ phase_id,
                                                 const float* __restrict__ anchor_mu,
                                                 const float* __restrict__ anchor_ls,
                                                 const float* __restrict__ tau0_raw,
                                                 const float* __restrict__ tau1_raw,
                                                 float* __restrict__ ws) {
    const int b   = blockIdx.x;
    const int tid = threadIdx.x;
    const int q   = tid & 15;        // channel quad
    const int p   = tid >> 4;        // row group 0..15

    // coalesced partial-sum accumulation: 16 rows per thread, float4
    float4 a1 = make_float4(0.f, 0.f, 0.f, 0.f);
    float4 a2 = make_float4(0.f, 0.f, 0.f, 0.f);
    float4 am = make_float4(0.f, 0.f, 0.f, 0.f);
#pragma unroll
    for (int i = 0; i < 16; ++i) {
        const int idx = (b * S_ + (p + i * 16)) * 16 + q;
        a1 = f4add(a1, ((const float4*)(ws + SUM_OFF))[idx]);
        a2 = f4add(a2, ((const float4*)(ws + SQ_OFF ))[idx]);
        am = f4add(am, ((const float4*)(ws + MS_OFF ))[idx]);
    }

    __shared__ float shf[3][16][64];
    *(float4*)&shf[0][p][q * 4] = a1;
    *(float4*)&shf[1][p][q * 4] = a2;
    *(float4*)&shf[2][p][q * 4] = am;
    __syncthreads();

    if (tid < 64) {
        // ---- gap merge: 256 tuples, 4 serial per lane + 6-step butterfly ----
        const int4* gp = (const int4*)((const int*)(ws + GAP_OFF)) + b * S_;
        int pre, suf, best, len;
        {
            int4 t0 = gp[tid * 4];
            pre = t0.x; suf = t0.y; best = t0.z; len = t0.w;
        }
#pragma unroll
        for (int k = 1; k < 4; ++k) {
            int4 r = gp[tid * 4 + k];
            merge_lr(pre, suf, best, len, r.x, r.y, r.z, r.w, pre, suf, best, len);
        }
#pragma unroll
        for (int m = 1; m < 64; m <<= 1) {
            int ppre = __shfl_xor(pre, m);
            int psuf = __shfl_xor(suf, m);
            int pbest = __shfl_xor(best, m);
            int plen = __shfl_xor(len, m);
            if (tid & m)   // partner is LEFT
                merge_lr(ppre, psuf, pbest, plen, pre, suf, best, len,
                         pre, suf, best, len);
            else           // partner is RIGHT
                merge_lr(pre, suf, best, len, ppre, psuf, pbest, plen,
                         pre, suf, best, len);
        }
        const float gap = (float)best / (float)T_;

        // ---- per-channel finalize ----
        const int c = tid;
        float sum = 0.f, sq = 0.f, ms = 0.f;
#pragma unroll
        for (int pp = 0; pp < 16; ++pp) {
            sum += shf[0][pp][c];
            sq  += shf[1][pp][c];
            ms  += shf[2][pp][c];
        }

        const float msc    = fmaxf(ms, EPS_);
        const float mu_obs = sum / msc;
        float var = (sq - 2.f * mu_obs * sum + mu_obs * mu_obs * ms) / msc;
        var = fmaxf(var, 0.f);
        const float sigma_obs = sqrtf(var + EPS_);
        const float coverage  = ms / (float)T_;

        const float t0 = log1pf(expf(tau0_raw[0]));   // softplus
        const float t1 = log1pf(expf(tau1_raw[0]));
        const float w  = coverage / (coverage + t0 + t1 * gap + EPS_);

        const int   pid    = phase_id[b];
        const float mu_ref = anchor_mu[pid * C_ + c];
        const float ls_ref = anchor_ls[pid * C_ + c];

        const float mu = w * mu_obs + (1.f - w) * mu_ref;
        const float ls = w * logf(sigma_obs + EPS_) + (1.f - w) * ls_ref;
        const float sigma = fmaxf(expf(ls), SIGMA_MIN_);

        ws[MU_OFF  + b * C_ + c] = mu;
        ws[INV_OFF + b * C_ + c] = 1.f / sigma;
    }
}

// ---------------- Kernel 3: elementwise normalize (bitmask, plain stores) ----
__global__ __launch_bounds__(256) void k3_norm(const float* __restrict__ x,
                                               const float* __restrict__ token,
                                               const float* __restrict__ ws,
                                               float* __restrict__ out) {
    const int gid = blockIdx.x * 256 + threadIdx.x;   // float4 index
    const float4* x4 = (const float4*)x;
    const float4* mu4  = (const float4*)(ws + MU_OFF);
    const float4* inv4 = (const float4*)(ws + INV_OFF);
    const float4* tk4  = (const float4*)token;

    const int b = gid >> 17;            // T_*C_/4 = 131072 float4 per b
    const int p = b * 16 + (gid & 15);  // (b, channel-quad)

    // mask bits: one wave-uniform 32B row per 64 float4s
    const unsigned long long* bw =
        (const unsigned long long*)(ws + BITS_OFF) + (size_t)(gid >> 6) * 4;
    const unsigned long long wx = bw[0];
    const unsigned long long wy = bw[1];
    const unsigned long long wz = bw[2];
    const unsigned long long wwd = bw[3];
    const int ln = gid & 63;

    float4 xv = x4[gid];
    float4 mu = mu4[p];
    float4 iv = inv4[p];
    float4 tk = tk4[gid & 15];

    float4 o;
    o.x = ((wx  >> ln) & 1) ? (xv.x - mu.x) * iv.x : tk.x;
    o.y = ((wy  >> ln) & 1) ? (xv.y - mu.y) * iv.y : tk.y;
    o.z = ((wz  >> ln) & 1) ? (xv.z - mu.z) * iv.z : tk.z;
    o.w = ((wwd >> ln) & 1) ? (xv.w - mu.w) * iv.w : tk.w;

    ((float4*)out)[gid] = o;
}

extern "C" void kernel_launch(void* const* d_in, const int* in_sizes, int n_in,
                              void* d_out, int out_size, void* d_ws, size_t ws_size,
                              hipStream_t stream) {
    const float* x    = (const float*)d_in[0];
    const float* mask = (const float*)d_in[1];
    const int*   pid  = (const int*)  d_in[2];
    const float* amu  = (const float*)d_in[3];
    const float* als  = (const float*)d_in[4];
    const float* t0   = (const float*)d_in[5];
    const float* t1   = (const float*)d_in[6];
    const float* tok  = (const float*)d_in[7];
    float* out = (float*)d_out;
    float* ws  = (float*)d_ws;

    k1x_stats<<<B_ * S_ / 4, 256, 0, stream>>>(x, ws);      // 2048 blocks, x only
    k1m_stats<<<B_ * S_ / 4, 256, 0, stream>>>(mask, ws);   // 2048 blocks, mask only
    k2_params<<<B_, 256, 0, stream>>>(pid, amu, als, t0, t1, ws);
    const int n4 = B_ * T_ * C_ / 4;          // 4194304 float4s
    k3_norm<<<n4 / 256, 256, 0, stream>>>(x, tok, ws, out);
}

// Round 9
// 62.399 us; speedup vs baseline: 1.0180x; 1.0180x over previous
//
#include <hip/hip_runtime.h>
#include <math.h>

// Problem constants (match reference)
#define B_ 32
#define T_ 8192
#define C_ 64
#define S_ 256           // t-chunks per batch row (chunk = 32 t = one wave's job)
#define L_ 32
#define EPS_ 1e-8f
#define SIGMA_MIN_ 1e-4f

// Workspace layout (float offsets); chunks = B_*S_ = 8192
#define SUM_OFF  0                       // 8192*64 = 524288
#define SQ_OFF   524288
#define MS_OFF   1048576
#define GAP_OFF  1572864                 // 8192 int4 = 32768 ints
#define BITS_OFF 1605632                 // 65536 rows * 4 u64 = 524288 floats
#define MU_OFF   2129920                 // B_*C_ = 2048
#define INV_OFF  2131968                 // 2048
// total = 2134016 floats ~= 8.1 MiB

__device__ inline float4 f4add(float4 a, float4 b) {
    return make_float4(a.x + b.x, a.y + b.y, a.z + b.z, a.w + b.w);
}
__device__ inline float4 f4shfl_xor(float4 v, int m) {
    float4 r;
    r.x = __shfl_xor(v.x, m);
    r.y = __shfl_xor(v.y, m);
    r.z = __shfl_xor(v.z, m);
    r.w = __shfl_xor(v.w, m);
    return r;
}
// ordered merge of run-tuples: acc(l) then r
__device__ inline void merge_lr(int l_pre, int l_suf, int l_best, int l_len,
                                int r_pre, int r_suf, int r_best, int r_len,
                                int& pre, int& suf, int& best, int& len) {
    best = max(max(l_best, r_best), l_suf + r_pre);
    pre  = (l_pre == l_len) ? l_len + r_pre : l_pre;
    suf  = (r_suf == r_len) ? r_len + l_suf : r_suf;
    len  = l_len + r_len;
}

// -------- Kernel 1: BOTH streams in one launch, interleaved blocks -----------
// even blocks: x-stats for chunk-group; odd blocks: mask-stats.
// Both streams co-resident -> 2x independent loads in flight machine-wide.
__global__ __launch_bounds__(256) void k1_all(const float* __restrict__ x,
                                              const float* __restrict__ mask,
                                              float* __restrict__ ws) {
    const int half = blockIdx.x & 1;           // 0 = x, 1 = mask
    const int blk  = blockIdx.x >> 1;          // 0..2047
    const int wv   = threadIdx.x >> 6;
    const int lane = threadIdx.x & 63;
    const int gw   = blk * 4 + wv;             // chunk id 0..8191
    const int base = gw * 512 + lane;          // float4 index

    if (half == 0) {
        // ---- x-only stats; two independent accumulator chains ----
        const float4* x4 = (const float4*)x;
        float4 s1a = make_float4(0.f, 0.f, 0.f, 0.f);
        float4 s1b = make_float4(0.f, 0.f, 0.f, 0.f);
        float4 s2a = make_float4(0.f, 0.f, 0.f, 0.f);
        float4 s2b = make_float4(0.f, 0.f, 0.f, 0.f);
#pragma unroll
        for (int it = 0; it < 8; it += 2) {
            const float4 va = x4[base + it * 64];
            const float4 vb = x4[base + (it + 1) * 64];
            s1a.x += va.x; s1a.y += va.y; s1a.z += va.z; s1a.w += va.w;
            s2a.x += va.x * va.x; s2a.y += va.y * va.y;
            s2a.z += va.z * va.z; s2a.w += va.w * va.w;
            s1b.x += vb.x; s1b.y += vb.y; s1b.z += vb.z; s1b.w += vb.w;
            s2b.x += vb.x * vb.x; s2b.y += vb.y * vb.y;
            s2b.z += vb.z * vb.z; s2b.w += vb.w * vb.w;
        }
        float4 s1 = f4add(s1a, s1b);
        float4 s2 = f4add(s2a, s2b);
        s1 = f4add(s1, f4shfl_xor(s1, 16)); s1 = f4add(s1, f4shfl_xor(s1, 32));
        s2 = f4add(s2, f4shfl_xor(s2, 16)); s2 = f4add(s2, f4shfl_xor(s2, 32));
        if (lane < 16) {
            ((float4*)(ws + SUM_OFF))[gw * 16 + lane] = s1;
            ((float4*)(ws + SQ_OFF ))[gw * 16 + lane] = s2;
        }
    } else {
        // ---- mask-only: counts, bit-pack, gap tuple ----
        const float4* m4 = (const float4*)mask;
        unsigned long long* bits = (unsigned long long*)(ws + BITS_OFF);

        float4 sma = make_float4(0.f, 0.f, 0.f, 0.f);
        float4 smb = make_float4(0.f, 0.f, 0.f, 0.f);
        unsigned int missw = 0;
#pragma unroll
        for (int it = 0; it < 8; ++it) {
            const float4 mv = m4[base + it * 64];
            if (it & 1) {
                smb.x += mv.x; smb.y += mv.y; smb.z += mv.z; smb.w += mv.w;
            } else {
                sma.x += mv.x; sma.y += mv.y; sma.z += mv.z; sma.w += mv.w;
            }
            // observed-bit words (1 = observed); bit index == lane
            unsigned long long obx = __ballot(mv.x >= 0.5f);
            unsigned long long oby = __ballot(mv.y >= 0.5f);
            unsigned long long obz = __ballot(mv.z >= 0.5f);
            unsigned long long obw = __ballot(mv.w >= 0.5f);
            if (lane < 4) {
                unsigned long long v = (lane == 0) ? obx : (lane == 1) ? oby
                                     : (lane == 2) ? obz : obw;
                bits[(size_t)(gw * 8 + it) * 4 + lane] = v;   // one 32B row / iter
            }
            // channel-0 missing bits live at lanes 0,16,32,48 of ~obx
            const unsigned long long nm = ~obx;
            const unsigned int nib =
                  (unsigned int)(nm & 1ull)
                | ((unsigned int)((nm >> 16) & 1ull) << 1)
                | ((unsigned int)((nm >> 32) & 1ull) << 2)
                | ((unsigned int)((nm >> 48) & 1ull) << 3);
            missw |= nib << (it * 4);
        }
        float4 sm = f4add(sma, smb);
        sm = f4add(sm, f4shfl_xor(sm, 16)); sm = f4add(sm, f4shfl_xor(sm, 32));
        if (lane < 16)
            ((float4*)(ws + MS_OFF))[gw * 16 + lane] = sm;

        if (lane == 0) {
            const unsigned int w = missw;      // bit i = chunk-local t missing
            int pre, suf, best;
            if (w == 0xFFFFFFFFu) {
                pre = 32; suf = 32; best = 32;
            } else {
                pre = __builtin_ctz(~w);
                suf = __builtin_clz(~w);
                unsigned int tmp = w; best = 0;
                while (tmp) { tmp &= (tmp << 1); ++best; }
            }
            ((int4*)((int*)(ws + GAP_OFF)))[gw] = make_int4(pre, suf, best, L_);
        }
    }
}

// ---------------- Kernel 2: combine partials -> per-(b,c) mu, 1/sigma --------
__global__ __launch_bounds__(256) void k2_params(const int*   __restrict__ phase_id,
                                                 const float* __restrict__ anchor_mu,
                                                 const float* __restrict__ anchor_ls,
                                                 const float* __restrict__ tau0_raw,
                                                 const float* __restrict__ tau1_raw,
                                                 float* __restrict__ ws) {
    const int b   = blockIdx.x;
    const int tid = threadIdx.x;
    const int q   = tid & 15;        // channel quad
    const int p   = tid >> 4;        // row group 0..15

    // coalesced partial-sum accumulation: 16 rows per thread, float4
    float4 a1 = make_float4(0.f, 0.f, 0.f, 0.f);
    float4 a2 = make_float4(0.f, 0.f, 0.f, 0.f);
    float4 am = make_float4(0.f, 0.f, 0.f, 0.f);
#pragma unroll
    for (int i = 0; i < 16; ++i) {
        const int idx = (b * S_ + (p + i * 16)) * 16 + q;
        a1 = f4add(a1, ((const float4*)(ws + SUM_OFF))[idx]);
        a2 = f4add(a2, ((const float4*)(ws + SQ_OFF ))[idx]);
        am = f4add(am, ((const float4*)(ws + MS_OFF ))[idx]);
    }

    __shared__ float shf[3][16][64];
    *(float4*)&shf[0][p][q * 4] = a1;
    *(float4*)&shf[1][p][q * 4] = a2;
    *(float4*)&shf[2][p][q * 4] = am;
    __syncthreads();

    if (tid < 64) {
        // ---- gap merge: 256 tuples, 4 serial per lane + 6-step butterfly ----
        const int4* gp = (const int4*)((const int*)(ws + GAP_OFF)) + b * S_;
        int pre, suf, best, len;
        {
            int4 t0 = gp[tid * 4];
            pre = t0.x; suf = t0.y; best = t0.z; len = t0.w;
        }
#pragma unroll
        for (int k = 1; k < 4; ++k) {
            int4 r = gp[tid * 4 + k];
            merge_lr(pre, suf, best, len, r.x, r.y, r.z, r.w, pre, suf, best, len);
        }
#pragma unroll
        for (int m = 1; m < 64; m <<= 1) {
            int ppre = __shfl_xor(pre, m);
            int psuf = __shfl_xor(suf, m);
            int pbest = __shfl_xor(best, m);
            int plen = __shfl_xor(len, m);
            if (tid & m)   // partner is LEFT
                merge_lr(ppre, psuf, pbest, plen, pre, suf, best, len,
                         pre, suf, best, len);
            else           // partner is RIGHT
                merge_lr(pre, suf, best, len, ppre, psuf, pbest, plen,
                         pre, suf, best, len);
        }
        const float gap = (float)best / (float)T_;

        // ---- per-channel finalize ----
        const int c = tid;
        float sum = 0.f, sq = 0.f, ms = 0.f;
#pragma unroll
        for (int pp = 0; pp < 16; ++pp) {
            sum += shf[0][pp][c];
            sq  += shf[1][pp][c];
            ms  += shf[2][pp][c];
        }

        const float msc    = fmaxf(ms, EPS_);
        const float mu_obs = sum / msc;
        float var = (sq - 2.f * mu_obs * sum + mu_obs * mu_obs * ms) / msc;
        var = fmaxf(var, 0.f);
        const float sigma_obs = sqrtf(var + EPS_);
        const float coverage  = ms / (float)T_;

        const float t0 = log1pf(expf(tau0_raw[0]));   // softplus
        const float t1 = log1pf(expf(tau1_raw[0]));
        const float w  = coverage / (coverage + t0 + t1 * gap + EPS_);

        const int   pid    = phase_id[b];
        const float mu_ref = anchor_mu[pid * C_ + c];
        const float ls_ref = anchor_ls[pid * C_ + c];

        const float mu = w * mu_obs + (1.f - w) * mu_ref;
        const float ls = w * logf(sigma_obs + EPS_) + (1.f - w) * ls_ref;
        const float sigma = fmaxf(expf(ls), SIGMA_MIN_);

        ws[MU_OFF  + b * C_ + c] = mu;
        ws[INV_OFF + b * C_ + c] = 1.f / sigma;
    }
}

// ---------------- Kernel 3: elementwise normalize (bitmask, plain stores) ----
__global__ __launch_bounds__(256) void k3_norm(const float* __restrict__ x,
                                               const float* __restrict__ token,
                                               const float* __restrict__ ws,
                                               float* __restrict__ out) {
    const int gid = blockIdx.x * 256 + threadIdx.x;   // float4 index
    const float4* x4 = (const float4*)x;
    const float4* mu4  = (const float4*)(ws + MU_OFF);
    const float4* inv4 = (const float4*)(ws + INV_OFF);
    const float4* tk4  = (const float4*)token;

    const int b = gid >> 17;            // T_*C_/4 = 131072 float4 per b
    const int p = b * 16 + (gid & 15);  // (b, channel-quad)

    // mask bits: one wave-uniform 32B row per 64 float4s
    const unsigned long long* bw =
        (const unsigned long long*)(ws + BITS_OFF) + (size_t)(gid >> 6) * 4;
    const unsigned long long wx = bw[0];
    const unsigned long long wy = bw[1];
    const unsigned long long wz = bw[2];
    const unsigned long long wwd = bw[3];
    const int ln = gid & 63;

    float4 xv = x4[gid];
    float4 mu = mu4[p];
    float4 iv = inv4[p];
    float4 tk = tk4[gid & 15];

    float4 o;
    o.x = ((wx  >> ln) & 1) ? (xv.x - mu.x) * iv.x : tk.x;
    o.y = ((wy  >> ln) & 1) ? (xv.y - mu.y) * iv.y : tk.y;
    o.z = ((wz  >> ln) & 1) ? (xv.z - mu.z) * iv.z : tk.z;
    o.w = ((wwd >> ln) & 1) ? (xv.w - mu.w) * iv.w : tk.w;

    ((float4*)out)[gid] = o;
}

extern "C" void kernel_launch(void* const* d_in, const int* in_sizes, int n_in,
                              void* d_out, int out_size, void* d_ws, size_t ws_size,
                              hipStream_t stream) {
    const float* x    = (const float*)d_in[0];
    const float* mask = (const float*)d_in[1];
    const int*   pid  = (const int*)  d_in[2];
    const float* amu  = (const float*)d_in[3];
    const float* als  = (const float*)d_in[4];
    const float* t0   = (const float*)d_in[5];
    const float* t1   = (const float*)d_in[6];
    const float* tok  = (const float*)d_in[7];
    float* out = (float*)d_out;
    float* ws  = (float*)d_ws;

    k1_all<<<B_ * S_ / 2, 256, 0, stream>>>(x, mask, ws);   // 4096 blocks, both streams
    k2_params<<<B_, 256, 0, stream>>>(pid, amu, als, t0, t1, ws);
    const int n4 = B_ * T_ * C_ / 4;          // 4194304 float4s
    k3_norm<<<n4 / 256, 256, 0, stream>>>(x, tok, ws, out);
}